// Round 1
// baseline (430.829 us; speedup 1.0000x reference)
//
#include <hip/hip_runtime.h>
#include <cstdint>

// DetNet NMS: W=8 groups x N=1024 dets x 5 channels (score, cx, cy, w, h).
// Pipeline: validity mask -> affine transform d = off + det*scale ->
// stable sort by score desc (tie: original index asc, matching jnp.argsort
// stable) -> greedy NMS (IoU > 0.3) -> output d_s * keep.
//
// Single workgroup of 1024 threads does the whole problem:
//  - the sort and the greedy-NMS loop are global dependency chains, so one
//    block avoids any grid sync; M=8192 keys fit in LDS (32KB+16KB).
//  - boxes for NMS are held in registers (8 positions/thread), flags as
//    bitmasks (no dynamic register indexing -> no scratch spills).
// All decision-critical FP math uses __f*_rn intrinsics to forbid FMA
// contraction: a 1-ulp difference at an IoU==0.3 or score-ordering boundary
// would flip an entire output row.

#define MTOT 8192
#define NTH  1024
#define EPT  8   // elements per thread

__global__ __launch_bounds__(NTH) void detnet_nms_kernel(
    const float* __restrict__ det,      // [8,1024,5]
    const float* __restrict__ offsets,  // [8,5]
    const float* __restrict__ scales,   // [8,5]
    const float* __restrict__ bounds,   // [8,4] = left,right,top,bottom
    float* __restrict__ out)            // [8192,5]
{
    __shared__ uint32_t skey[MTOT];   // ~monotone(score bits): ascending sort => score desc
    __shared__ uint16_t sidx[MTOT];   // original index (tie-break asc = stable argsort)
    __shared__ float soff[40];
    __shared__ float sscl[40];
    __shared__ float sbnd[32];
    __shared__ float bbox[5];         // broadcast kept box: x1,y1,x2,y2,area
    __shared__ int   winner;

    const int t = threadIdx.x;
    if (t < 40) { soff[t] = offsets[t]; sscl[t] = scales[t]; }
    if (t < 32) { sbnd[t] = bounds[t]; }
    __syncthreads();

    // ---- Phase 1: scores + sort keys -------------------------------------
    #pragma unroll
    for (int s = 0; s < EPT; ++s) {
        int i = t + s * NTH;
        int g = i >> 10;                        // w-group
        float raw_s = det[i * 5 + 0];
        float cx    = det[i * 5 + 1];
        float cy    = det[i * 5 + 2];
        float score = __fadd_rn(soff[g * 5 + 0], __fmul_rn(raw_s, sscl[g * 5 + 0]));
        float L  = sbnd[g * 4 + 0], R  = sbnd[g * 4 + 1];
        float Tb = sbnd[g * 4 + 2], Bb = sbnd[g * 4 + 3];
        bool valid = (cx < R) && (cx > L) && (cy < Bb) && (cy > Tb);
        float sv = valid ? score : -1.0f;
        uint32_t u = __float_as_uint(sv);
        // monotone float->uint map (ascending), then invert for descending
        uint32_t m = (u & 0x80000000u) ? ~u : (u | 0x80000000u);
        skey[i] = ~m;
        sidx[i] = (uint16_t)i;
    }
    __syncthreads();

    // ---- Phase 2: bitonic sort, ascending lexicographic on (skey, sidx) --
    for (int k = 2; k <= MTOT; k <<= 1) {
        for (int j = k >> 1; j > 0; j >>= 1) {
            #pragma unroll
            for (int s = 0; s < EPT; ++s) {
                int i = t + s * NTH;
                int ixj = i ^ j;
                if (ixj > i) {   // each unordered pair handled exactly once
                    uint32_t ka = skey[i], kb = skey[ixj];
                    uint16_t ia = sidx[i], ib = sidx[ixj];
                    bool gt = (ka > kb) || ((ka == kb) && (ia > ib));
                    if (((i & k) == 0) ? gt : !gt) {
                        skey[i] = kb; skey[ixj] = ka;
                        sidx[i] = ib; sidx[ixj] = ia;
                    }
                }
            }
            __syncthreads();
        }
    }

    // ---- Phase 3: per-thread boxes (registers) ---------------------------
    float x1[EPT], y1[EPT], x2[EPT], y2[EPT], ar[EPT];
    int candm = 0, suppm = 0, keptm = 0;   // bitmasks over the 8 slots
    #pragma unroll
    for (int s = 0; s < EPT; ++s) {
        int pos = t + s * NTH;
        int idx = (int)sidx[pos];
        uint32_t m = ~skey[pos];
        if (m > 0x80000000u) candm |= (1 << s);   // score > 0.0 (ref keep cond)
        int g = idx >> 10;
        float dcx = __fadd_rn(soff[g*5+1], __fmul_rn(det[idx*5+1], sscl[g*5+1]));
        float dcy = __fadd_rn(soff[g*5+2], __fmul_rn(det[idx*5+2], sscl[g*5+2]));
        float dw  = __fadd_rn(soff[g*5+3], __fmul_rn(det[idx*5+3], sscl[g*5+3]));
        float dh  = __fadd_rn(soff[g*5+4], __fmul_rn(det[idx*5+4], sscl[g*5+4]));
        float hw = __fmul_rn(dw, 0.5f), hh = __fmul_rn(dh, 0.5f);
        x1[s] = __fsub_rn(dcx, hw);
        y1[s] = __fsub_rn(dcy, hh);
        x2[s] = __fadd_rn(dcx, hw);
        y2[s] = __fadd_rn(dcy, hh);
        ar[s] = __fmul_rn(fmaxf(__fsub_rn(x2[s], x1[s]), 0.0f),
                          fmaxf(__fsub_rn(y2[s], y1[s]), 0.0f));
    }
    __syncthreads();

    // ---- Phase 4: greedy NMS (K iterations, K = #kept) -------------------
    int cur = -1;
    while (true) {
        if (t == 0) winner = MTOT;
        __syncthreads();
        // first unsuppressed candidate position > cur
        int local = MTOT;
        #pragma unroll
        for (int s = 0; s < EPT; ++s) {
            int pos = t + s * NTH;
            if ((candm & (1 << s)) && !(suppm & (1 << s)) && pos > cur && pos < local)
                local = pos;
        }
        #pragma unroll
        for (int o = 32; o > 0; o >>= 1)
            local = min(local, __shfl_down(local, o));
        if ((t & 63) == 0) atomicMin(&winner, local);
        __syncthreads();
        int w = winner;
        if (w >= MTOT) break;                       // uniform exit
        if (t == 0) {
            // recompute winner's box from global (L1-hot) to avoid dynamic
            // register-array indexing
            int idx = (int)sidx[w];
            int g = idx >> 10;
            float dcx = __fadd_rn(soff[g*5+1], __fmul_rn(det[idx*5+1], sscl[g*5+1]));
            float dcy = __fadd_rn(soff[g*5+2], __fmul_rn(det[idx*5+2], sscl[g*5+2]));
            float dw  = __fadd_rn(soff[g*5+3], __fmul_rn(det[idx*5+3], sscl[g*5+3]));
            float dh  = __fadd_rn(soff[g*5+4], __fmul_rn(det[idx*5+4], sscl[g*5+4]));
            float hw = __fmul_rn(dw, 0.5f), hh = __fmul_rn(dh, 0.5f);
            float bx1 = __fsub_rn(dcx, hw), by1 = __fsub_rn(dcy, hh);
            float bx2 = __fadd_rn(dcx, hw), by2 = __fadd_rn(dcy, hh);
            bbox[0] = bx1; bbox[1] = by1; bbox[2] = bx2; bbox[3] = by2;
            bbox[4] = __fmul_rn(fmaxf(__fsub_rn(bx2, bx1), 0.0f),
                                fmaxf(__fsub_rn(by2, by1), 0.0f));
        }
        if ((w & (NTH - 1)) == t) {                 // owner marks kept
            int s = w >> 10;
            keptm |= (1 << s);
            suppm |= (1 << s);
        }
        __syncthreads();
        float bx1 = bbox[0], by1 = bbox[1], bx2 = bbox[2], by2 = bbox[3], ba = bbox[4];
        #pragma unroll
        for (int s = 0; s < EPT; ++s) {
            int pos = t + s * NTH;
            if (pos > w && (candm & (1 << s)) && !(suppm & (1 << s))) {
                float iw = fmaxf(__fsub_rn(fminf(x2[s], bx2), fmaxf(x1[s], bx1)), 0.0f);
                float ih = fmaxf(__fsub_rn(fminf(y2[s], by2), fmaxf(y1[s], by1)), 0.0f);
                float inter = __fmul_rn(iw, ih);
                float uni   = __fsub_rn(__fadd_rn(ba, ar[s]), inter);
                float iou   = __fdiv_rn(inter, fmaxf(uni, 1e-9f));
                if (iou > 0.3f) suppm |= (1 << s);
            }
        }
        cur = w;
    }

    // ---- Phase 5: output = d_s * keep ------------------------------------
    #pragma unroll
    for (int s = 0; s < EPT; ++s) {
        int pos = t + s * NTH;
        float v0 = 0.f, v1 = 0.f, v2 = 0.f, v3 = 0.f, v4 = 0.f;
        if (keptm & (1 << s)) {
            int idx = (int)sidx[pos];
            int g = idx >> 10;
            v0 = __fadd_rn(soff[g*5+0], __fmul_rn(det[idx*5+0], sscl[g*5+0]));
            v1 = __fadd_rn(soff[g*5+1], __fmul_rn(det[idx*5+1], sscl[g*5+1]));
            v2 = __fadd_rn(soff[g*5+2], __fmul_rn(det[idx*5+2], sscl[g*5+2]));
            v3 = __fadd_rn(soff[g*5+3], __fmul_rn(det[idx*5+3], sscl[g*5+3]));
            v4 = __fadd_rn(soff[g*5+4], __fmul_rn(det[idx*5+4], sscl[g*5+4]));
        }
        out[pos * 5 + 0] = v0;
        out[pos * 5 + 1] = v1;
        out[pos * 5 + 2] = v2;
        out[pos * 5 + 3] = v3;
        out[pos * 5 + 4] = v4;
    }
}

extern "C" void kernel_launch(void* const* d_in, const int* in_sizes, int n_in,
                              void* d_out, int out_size, void* d_ws, size_t ws_size,
                              hipStream_t stream) {
    const float* det     = (const float*)d_in[0];
    const float* offsets = (const float*)d_in[1];
    const float* scales  = (const float*)d_in[2];
    const float* bounds  = (const float*)d_in[3];
    float* out = (float*)d_out;
    detnet_nms_kernel<<<1, NTH, 0, stream>>>(det, offsets, scales, bounds, out);
}